// Round 5
// baseline (278.362 us; speedup 1.0000x reference)
//
#include <hip/hip_runtime.h>
#include <cmath>

typedef unsigned short u16;
typedef __bf16 bf16x8 __attribute__((ext_vector_type(8)));
typedef float f32x4 __attribute__((ext_vector_type(4)));

__device__ __forceinline__ u16 f2bf(float f) {
  unsigned u = __float_as_uint(f);
  u += 0x7fffu + ((u >> 16) & 1u);
  return (u16)(u >> 16);
}
__device__ __forceinline__ float bf2f(u16 h) {
  return __uint_as_float(((unsigned)h) << 16);
}
__device__ __forceinline__ f32x4 mfma_bf16(bf16x8 a, bf16x8 b, f32x4 c) {
  return __builtin_amdgcn_mfma_f32_16x16x32_bf16(a, b, c, 0, 0, 0);
}
__device__ __forceinline__ float gelu_exact(float x) {
  return 0.5f * x * (1.0f + erff(x * 0.70710678118654752440f));
}

// B=16, C=128, H=64, W=64. Padded NHWC: [B][66][66][128], data at y+1,x+1.
__device__ __forceinline__ size_t pidx(int b, int y, int x) {
  return ((size_t)(b * 66 + y) * 66 + x) * 128;
}

// map border position index k in [0,260) -> (y,x) on the padded frame
__device__ __forceinline__ void border_yx(int k, int& y, int& x) {
  if (k < 66) { y = 0; x = k; }
  else if (k < 132) { y = 65; x = k - 66; }
  else if (k < 196) { y = k - 131; x = 0; }
  else { y = k - 195; x = 65; }
}

// ---------------- pack: X -> padded NHWC bf16, weights -> B-frag, X borders=0
__global__ __launch_bounds__(256) void pack_xw(
    const float* __restrict__ Fin, u16* __restrict__ Xp,
    const float* __restrict__ w0, const float* __restrict__ w1,
    const float* __restrict__ w2, const float* __restrict__ w3,
    const float* __restrict__ w4, u16* __restrict__ Wpk) {
  const int tid = threadIdx.x;
  const int bid = blockIdx.x;
  if (bid < 1024) {
    __shared__ float T[64 * 129];
    const int b = bid >> 6, y = bid & 63;
#pragma unroll
    for (int i = 0; i < 32; ++i) {
      int idx = tid + i * 256;
      int c = idx >> 6, x = idx & 63;
      T[x * 129 + c] = Fin[(size_t)(b * 128 + c) * 4096 + y * 64 + x];
    }
    __syncthreads();
#pragma unroll
    for (int i = 0; i < 4; ++i) {
      int chunk = tid + i * 256;
      int x = chunk >> 4;
      int c0 = (chunk & 15) * 8;
      u16 tmp[8];
#pragma unroll
      for (int e = 0; e < 8; ++e) tmp[e] = f2bf(T[x * 129 + c0 + e]);
      *reinterpret_cast<uint4*>(Xp + pidx(b, y + 1, x + 1) + c0) =
          *reinterpret_cast<const uint4*>(tmp);
    }
  } else if (bid < 1384) {
    int gid = (bid - 1024) * 256 + tid;  // 92160 total
    int lane = gid & 63;
    int nblk = (gid >> 6) & 7;
    int step = (gid >> 9) % 36;
    int conv = gid / (512 * 36);
    if (conv >= 5) return;
    const float* w = conv == 0 ? w0 : conv == 1 ? w1 : conv == 2 ? w2 : conv == 3 ? w3 : w4;
    int tap = step >> 2, cc = step & 3;
    int dy = tap / 3, dx = tap % 3;
    int co = nblk * 16 + (lane & 15);
    int ci0 = cc * 32 + (lane >> 4) * 8;
    u16 tmp[8];
#pragma unroll
    for (int e = 0; e < 8; ++e)
      tmp[e] = f2bf(w[((size_t)(co * 128 + ci0 + e) * 3 + dy) * 3 + dx]);
    size_t off = ((size_t)conv * 36 * 8 * 64 + (size_t)((step * 8 + nblk) * 64 + lane)) * 8;
    *reinterpret_cast<uint4*>(Wpk + off) = *reinterpret_cast<const uint4*>(tmp);
  } else {
    // zero Xp borders: 4160 positions of 256B
    int p = (bid - 1384) * 16 + (tid >> 4);  // 260*16 = 4160
    int b = p / 260, k = p % 260;
    int y, x;
    border_yx(k, y, x);
    *reinterpret_cast<uint4*>(Xp + pidx(b, y, x) + (tid & 15) * 8) =
        make_uint4(0u, 0u, 0u, 0u);
  }
}

// ---------------- fused QKV conv3x3, padded-global A, M128xN64 ----------------
__global__ __launch_bounds__(256, 3) void conv_qkv(
    const u16* __restrict__ Xp, const u16* __restrict__ Wp,
    const float* __restrict__ qb, const float* __restrict__ kb,
    const float* __restrict__ vb, u16* __restrict__ QP,
    u16* __restrict__ KP, u16* __restrict__ Vout) {
  __shared__ alignas(16) u16 Ts[128 * 72];  // 18432 B epilogue buffer
  const int tid = threadIdx.x;
  const int lane = tid & 63;
  const int wv = tid >> 6;
  const int wm = wv >> 1, wn = wv & 1;
  int mt = blockIdx.x;
  mt = (mt & 7) * 128 + (mt >> 3);  // 1024 blocks, bijective XCD swizzle
  const int b = mt >> 6;
  const int r = mt & 63;
  const int yp = r >> 1;
  const int nh = r & 1;
  const int y0 = yp * 2;
  const int lm = lane & 15, lq = lane >> 4;

  const char* ab[4];
#pragma unroll
  for (int i = 0; i < 4; ++i) {
    int pos = wm * 64 + i * 16 + lm;
    int y = y0 + (pos >> 6), x = pos & 63;
    ab[i] = reinterpret_cast<const char*>(Xp + pidx(b, y, x) + lq * 8);
  }
  const char* wb = reinterpret_cast<const char*>(
      Wp + (size_t)(((nh * 4 + wn * 2) * 64) + lane) * 8);

  f32x4 acc[3][4][2];
#pragma unroll
  for (int c = 0; c < 3; ++c)
#pragma unroll
    for (int i = 0; i < 4; ++i)
#pragma unroll
      for (int j = 0; j < 2; ++j) acc[c][i][j] = f32x4{0.f, 0.f, 0.f, 0.f};

#pragma unroll 1
  for (int s = 0; s < 36; ++s) {
    const int tap = s >> 2, cc = s & 3;
    const int dy = (tap * 11) >> 5;
    const int dx = tap - dy * 3;
    const int aoff = dy * 16896 + dx * 256 + cc * 64;
    bf16x8 af[4], bfr[6];
#pragma unroll
    for (int i = 0; i < 4; ++i)
      af[i] = *reinterpret_cast<const bf16x8*>(ab[i] + aoff);
#pragma unroll
    for (int cv = 0; cv < 3; ++cv)
#pragma unroll
      for (int j = 0; j < 2; ++j)
        bfr[cv * 2 + j] = *reinterpret_cast<const bf16x8*>(
            wb + cv * 294912 + s * 8192 + j * 1024);
#pragma unroll
    for (int cv = 0; cv < 3; ++cv)
#pragma unroll
      for (int i = 0; i < 4; ++i)
#pragma unroll
        for (int j = 0; j < 2; ++j)
          acc[cv][i][j] = mfma_bf16(af[i], bfr[cv * 2 + j], acc[cv][i][j]);
  }

  // ---- Q, K: fragment-packed epilogue ----
#pragma unroll
  for (int cv = 0; cv < 2; ++cv) {
    const float* bias = cv == 0 ? qb : kb;
    u16* OutB = cv == 0 ? QP : KP;
#pragma unroll
    for (int i = 0; i < 4; ++i)
#pragma unroll
      for (int j = 0; j < 2; ++j) {
        int nloc = wn * 32 + j * 16 + lm;
        float bs = bias[nh * 64 + nloc];
#pragma unroll
        for (int rr = 0; rr < 4; ++rr) {
          int m = wm * 64 + i * 16 + lq * 4 + rr;
          Ts[nloc * 136 + m] = f2bf(acc[cv][i][j][rr] + bs);
        }
      }
    __syncthreads();
#pragma unroll
    for (int it = 0; it < 4; ++it) {
      int item = tid + it * 256;  // 0..1023
      int l = item & 63, cbl = (item >> 6) & 3, ksl = item >> 8;
      int c = cbl * 16 + (l & 15);
      int mloc = ksl * 32 + (l >> 4) * 8;
      int ks = yp * 4 + ksl, cb = nh * 4 + cbl;
      *reinterpret_cast<uint4*>(
          OutB + (size_t)(((b * 128 + ks) * 8 + cb) * 64 + l) * 8) =
          *reinterpret_cast<const uint4*>(Ts + c * 136 + mloc);
    }
    __syncthreads();
  }

  // ---- V: natural [pos][ch] ----
#pragma unroll
  for (int i = 0; i < 4; ++i)
#pragma unroll
    for (int j = 0; j < 2; ++j) {
      int nloc = wn * 32 + j * 16 + lm;
      float bs = vb[nh * 64 + nloc];
#pragma unroll
      for (int rr = 0; rr < 4; ++rr) {
        int m = wm * 64 + i * 16 + lq * 4 + rr;
        Ts[m * 72 + nloc] = f2bf(acc[2][i][j][rr] + bs);
      }
    }
  __syncthreads();
  {
    int rr = tid >> 1, q = tid & 1;
    const uint4* src = reinterpret_cast<const uint4*>(Ts + rr * 72 + q * 32);
    uint4* dst = reinterpret_cast<uint4*>(
        Vout + ((size_t)((b * 32 + yp) * 128 + rr) * 128 + nh * 64 + q * 32));
#pragma unroll
    for (int k = 0; k < 4; ++k) dst[k] = src[k];
  }
}

// ---------------- FFN convs, padded-global A, M128xN128 ----------------
// MODE 1: gelu -> padded bf16 out (Hp)
// MODE 2: f32 NCHW out + residual from padded Fp
template <int MODE>
__global__ __launch_bounds__(256, 4) void conv_ffn(
    const u16* __restrict__ Xin, const u16* __restrict__ Wp,
    const float* __restrict__ bias, u16* __restrict__ OutP,
    float* __restrict__ OutF, const u16* __restrict__ Resid) {
  const int tid = threadIdx.x;
  const int lane = tid & 63;
  const int wv = tid >> 6;
  const int wm = wv >> 1, wn = wv & 1;
  int mt = blockIdx.x;
  mt = (mt & 7) * 64 + (mt >> 3);  // 512 blocks, bijective XCD swizzle
  const int b = mt >> 5;
  const int yp = mt & 31;
  const int y0 = yp * 2;
  const int lm = lane & 15, lq = lane >> 4;

  const char* ab[4];
#pragma unroll
  for (int i = 0; i < 4; ++i) {
    int pos = wm * 64 + i * 16 + lm;
    int y = y0 + (pos >> 6), x = pos & 63;
    ab[i] = reinterpret_cast<const char*>(Xin + pidx(b, y, x) + lq * 8);
  }
  const char* wb = reinterpret_cast<const char*>(
      Wp + (size_t)((wn * 4 * 64) + lane) * 8);

  f32x4 acc[4][4];
#pragma unroll
  for (int i = 0; i < 4; ++i)
#pragma unroll
    for (int j = 0; j < 4; ++j) acc[i][j] = f32x4{0.f, 0.f, 0.f, 0.f};

#pragma unroll 1
  for (int s = 0; s < 36; ++s) {
    const int tap = s >> 2, cc = s & 3;
    const int dy = (tap * 11) >> 5;
    const int dx = tap - dy * 3;
    const int aoff = dy * 16896 + dx * 256 + cc * 64;
    bf16x8 af[4], bfr[4];
#pragma unroll
    for (int i = 0; i < 4; ++i)
      af[i] = *reinterpret_cast<const bf16x8*>(ab[i] + aoff);
#pragma unroll
    for (int j = 0; j < 4; ++j)
      bfr[j] = *reinterpret_cast<const bf16x8*>(wb + s * 8192 + j * 1024);
#pragma unroll
    for (int i = 0; i < 4; ++i)
#pragma unroll
      for (int j = 0; j < 4; ++j) acc[i][j] = mfma_bf16(af[i], bfr[j], acc[i][j]);
  }

  if constexpr (MODE == 1) {
    __shared__ u16 T[128 * 136];
#pragma unroll
    for (int i = 0; i < 4; ++i)
#pragma unroll
      for (int j = 0; j < 4; ++j) {
        int n = wn * 64 + j * 16 + lm;
        float bs = bias[n];
#pragma unroll
        for (int r = 0; r < 4; ++r) {
          int m = wm * 64 + i * 16 + lq * 4 + r;
          T[m * 136 + n] = f2bf(gelu_exact(acc[i][j][r] + bs));
        }
      }
    __syncthreads();
    int rr = tid >> 1, hf = tid & 1;
    int y = y0 + (rr >> 6), x = rr & 63;
    const uint4* src = reinterpret_cast<const uint4*>(T + rr * 136 + hf * 64);
    uint4* dst = reinterpret_cast<uint4*>(OutP + pidx(b, y + 1, x + 1) + hf * 64);
#pragma unroll
    for (int k = 0; k < 8; ++k) dst[k] = src[k];
  } else {
    // direct f32 NCHW stores + residual (no LDS)
#pragma unroll
    for (int i = 0; i < 4; ++i)
#pragma unroll
      for (int j = 0; j < 4; ++j) {
        int n = wn * 64 + j * 16 + lm;
        float bs = bias[n];
        int m0 = wm * 64 + i * 16 + lq * 4;
        int y = y0 + (m0 >> 6), x = m0 & 63;
        const u16* rp = Resid + pidx(b, y + 1, x + 1) + n;
        float4 v;
        v.x = acc[i][j][0] + bs + bf2f(rp[0]);
        v.y = acc[i][j][1] + bs + bf2f(rp[128]);
        v.z = acc[i][j][2] + bs + bf2f(rp[256]);
        v.w = acc[i][j][3] + bs + bf2f(rp[384]);
        *reinterpret_cast<float4*>(
            OutF + ((size_t)(b * 128 + n) * 4096 + yp * 128 + m0)) = v;
      }
  }
}

// ---------------- S = K^T Q, split-K=8 -> f32 partials ----------------
__global__ __launch_bounds__(256, 2) void attn_s(const u16* __restrict__ QP,
                                                 const u16* __restrict__ KP,
                                                 float* __restrict__ SP) {
  const int tid = threadIdx.x;
  const int lane = tid & 63;
  const int wv = tid >> 6, wm = wv >> 1, wn = wv & 1;
  const int lm = lane & 15, lq = lane >> 4;
  int mt = blockIdx.x;
  mt = (mt & 7) * 16 + (mt >> 3);  // 128 blocks, bijective
  const int b = mt >> 3, sp = mt & 7;

  f32x4 acc[4][4];
#pragma unroll
  for (int i = 0; i < 4; ++i)
#pragma unroll
    for (int j = 0; j < 4; ++j) acc[i][j] = f32x4{0.f, 0.f, 0.f, 0.f};

#pragma unroll
  for (int ksl = 0; ksl < 16; ++ksl) {
    const int ks = sp * 16 + ksl;
    bf16x8 af[4], bfr[4];
#pragma unroll
    for (int i = 0; i < 4; ++i)
      af[i] = *reinterpret_cast<const bf16x8*>(
          KP + (size_t)(((b * 128 + ks) * 8 + wm * 4 + i) * 64 + lane) * 8);
#pragma unroll
    for (int j = 0; j < 4; ++j)
      bfr[j] = *reinterpret_cast<const bf16x8*>(
          QP + (size_t)(((b * 128 + ks) * 8 + wn * 4 + j) * 64 + lane) * 8);
#pragma unroll
    for (int i = 0; i < 4; ++i)
#pragma unroll
      for (int j = 0; j < 4; ++j) acc[i][j] = mfma_bf16(af[i], bfr[j], acc[i][j]);
  }

  float* out = SP + (size_t)(b * 8 + sp) * 16384;
#pragma unroll
  for (int i = 0; i < 4; ++i)
#pragma unroll
    for (int j = 0; j < 4; ++j)
#pragma unroll
      for (int r = 0; r < 4; ++r)
        out[(wm * 64 + i * 16 + lq * 4 + r) * 128 + wn * 64 + j * 16 + lm] =
            acc[i][j][r];
}

// ---------------- reduce partials + softmax + pack A ----------------
__global__ __launch_bounds__(256) void attn_r(const float* __restrict__ SP,
                                              u16* __restrict__ ABP) {
  __shared__ float Sf[32][129];
  __shared__ float Inv[32];
  const int tid = threadIdx.x;
  const int b = blockIdx.x >> 2, eb = blockIdx.x & 3;

#pragma unroll
  for (int it = 0; it < 16; ++it) {
    int id = it * 256 + tid;
    int rl = id >> 7, d = id & 127;
    const float* p = SP + (size_t)b * 8 * 16384 + (size_t)(eb * 32 + rl) * 128 + d;
    float s = 0.f;
#pragma unroll
    for (int sp = 0; sp < 8; ++sp) s += p[(size_t)sp * 16384];
    Sf[rl][d] = s * 0.015625f;
  }
  __syncthreads();

  {
    int rl = tid >> 3, sub = tid & 7;
    float mx = -3.4e38f;
#pragma unroll
    for (int k = 0; k < 16; ++k) mx = fmaxf(mx, Sf[rl][sub + 8 * k]);
    mx = fmaxf(mx, __shfl_xor(mx, 1));
    mx = fmaxf(mx, __shfl_xor(mx, 2));
    mx = fmaxf(mx, __shfl_xor(mx, 4));
    float s = 0.f;
#pragma unroll
    for (int k = 0; k < 16; ++k) {
      float e = __expf(Sf[rl][sub + 8 * k] - mx);
      Sf[rl][sub + 8 * k] = e;
      s += e;
    }
    s += __shfl_xor(s, 1);
    s += __shfl_xor(s, 2);
    s += __shfl_xor(s, 4);
    if (sub == 0) Inv[rl] = 1.0f / s;
  }
  __syncthreads();

#pragma unroll
  for (int it = 0; it < 2; ++it) {
    int item = tid + it * 256;
    int l = item & 63, nb = item >> 6;
    int d = nb * 16 + (l & 15);
    u16 tmp[8];
#pragma unroll
    for (int e = 0; e < 8; ++e) {
      int rloc = (l >> 4) * 8 + e;
      tmp[e] = f2bf(Sf[rloc][d] * Inv[rloc]);
    }
    *reinterpret_cast<uint4*>(ABP + (size_t)(((b * 4 + eb) * 8 + nb) * 64 + l) * 8) =
        *reinterpret_cast<const uint4*>(tmp);
  }
}

// ---------------- M = Pspe @ A, pack M ----------------
__global__ __launch_bounds__(256, 1) void attn_m(const float* __restrict__ Pspe,
                                                 const u16* __restrict__ ABP,
                                                 u16* __restrict__ Mpack) {
  __shared__ u16 Ml[128 * 136];
  const int b = blockIdx.x;
  const int tid = threadIdx.x;
  const int lane = tid & 63;
  const int wv = tid >> 6, wm = wv >> 1, wn = wv & 1;
  const int lm = lane & 15, lq = lane >> 4;

  f32x4 acc[4][4];
#pragma unroll
  for (int i = 0; i < 4; ++i)
#pragma unroll
    for (int j = 0; j < 4; ++j) acc[i][j] = f32x4{0.f, 0.f, 0.f, 0.f};

  const float* P = Pspe + (size_t)b * 128 * 128;
#pragma unroll
  for (int cc = 0; cc < 4; ++cc) {
    int e0 = cc * 32 + lq * 8;
    bf16x8 af[4], bfr[4];
#pragma unroll
    for (int i = 0; i < 4; ++i) {
      const float* p = P + (size_t)(wm * 64 + i * 16 + lm) * 128 + e0;
      union { u16 u[8]; bf16x8 v; } cv;
#pragma unroll
      for (int e = 0; e < 8; ++e) cv.u[e] = f2bf(p[e]);
      af[i] = cv.v;
    }
#pragma unroll
    for (int j = 0; j < 4; ++j)
      bfr[j] = *reinterpret_cast<const bf16x8*>(
          ABP + (size_t)(((b * 4 + cc) * 8 + wn * 4 + j) * 64 + lane) * 8);
#pragma unroll
    for (int i = 0; i < 4; ++i)
#pragma unroll
      for (int j = 0; j < 4; ++j) acc[i][j] = mfma_bf16(af[i], bfr[j], acc[i][j]);
  }

#pragma unroll
  for (int i = 0; i < 4; ++i)
#pragma unroll
    for (int j = 0; j < 4; ++j)
#pragma unroll
      for (int r = 0; r < 4; ++r)
        Ml[(wn * 64 + j * 16 + lm) * 136 + (wm * 64 + i * 16 + lq * 4 + r)] =
            f2bf(acc[i][j][r]);
  __syncthreads();

#pragma unroll
  for (int it = 0; it < 8; ++it) {
    int item = tid + it * 256;
    int l2 = item & 63, nb = (item >> 6) & 7, cc2 = item >> 9;
    int d = nb * 16 + (l2 & 15), c0 = cc2 * 32 + (l2 >> 4) * 8;
    *reinterpret_cast<uint4*>(Mpack + (size_t)b * 16384 + (size_t)item * 8) =
        *reinterpret_cast<const uint4*>(Ml + d * 136 + c0);
  }
}

// ---------------- F3 = V @ M -> Fp (padded) + zero Fp/Hp borders ----------
__global__ __launch_bounds__(256) void f3_gemm(const u16* __restrict__ V,
                                               const u16* __restrict__ Mpack,
                                               u16* __restrict__ Fp,
                                               u16* __restrict__ Hp) {
  const int tid = threadIdx.x;
  const int lane = tid & 63;
  const int wv = tid >> 6, wm = wv >> 1, wn = wv & 1;
  const int lm = lane & 15, lq = lane >> 4;
  const int bid = blockIdx.x;
  int mt = bid;
  mt = (mt & 7) * 64 + (mt >> 3);
  const int b = mt >> 5;
  const int yp = mt & 31;

  f32x4 acc[4][4];
#pragma unroll
  for (int i = 0; i < 4; ++i)
#pragma unroll
    for (int j = 0; j < 4; ++j) acc[i][j] = f32x4{0.f, 0.f, 0.f, 0.f};

#pragma unroll
  for (int cc = 0; cc < 4; ++cc) {
    int k0 = cc * 32 + lq * 8;
    bf16x8 af[4], bfr[4];
#pragma unroll
    for (int i = 0; i < 4; ++i)
      af[i] = *reinterpret_cast<const bf16x8*>(
          V + (size_t)(mt * 128 + wm * 64 + i * 16 + lm) * 128 + k0);
#pragma unroll
    for (int j = 0; j < 4; ++j)
      bfr[j] = *reinterpret_cast<const bf16x8*>(
          Mpack + (size_t)b * 16384 + (size_t)((cc * 8 + wn * 4 + j) * 64 + lane) * 8);
#pragma unroll
    for (int i = 0; i < 4; ++i)
#pragma unroll
      for (int j = 0; j < 4; ++j) acc[i][j] = mfma_bf16(af[i], bfr[j], acc[i][j]);
  }

  // zero borders of Fp and Hp (independent of main work)
#pragma unroll
  for (int rep = 0; rep < 2; ++rep) {
    int p = bid * 32 + rep * 16 + (tid >> 4);
    if (p < 8320) {
      u16* buf = p < 4160 ? Fp : Hp;
      int q = p < 4160 ? p : p - 4160;
      int bb = q / 260, k = q % 260;
      int y, x;
      border_yx(k, y, x);
      *reinterpret_cast<uint4*>(buf + pidx(bb, y, x) + (tid & 15) * 8) =
          make_uint4(0u, 0u, 0u, 0u);
    }
  }

  __shared__ u16 T[128 * 136];
#pragma unroll
  for (int i = 0; i < 4; ++i)
#pragma unroll
    for (int j = 0; j < 4; ++j)
#pragma unroll
      for (int r = 0; r < 4; ++r)
        T[(wm * 64 + i * 16 + lq * 4 + r) * 136 + wn * 64 + j * 16 + lm] =
            f2bf(acc[i][j][r]);
  __syncthreads();
  int rr = tid >> 1, hf = tid & 1;
  int y = yp * 2 + (rr >> 6), x = rr & 63;
  const uint4* src = reinterpret_cast<const uint4*>(T + rr * 136 + hf * 64);
  uint4* dst = reinterpret_cast<uint4*>(Fp + pidx(b, y + 1, x + 1) + hf * 64);
#pragma unroll
  for (int k = 0; k < 8; ++k) dst[k] = src[k];
}

extern "C" void kernel_launch(void* const* d_in, const int* in_sizes, int n_in,
                              void* d_out, int out_size, void* d_ws, size_t ws_size,
                              hipStream_t stream) {
  const float* F_in = (const float*)d_in[0];
  const float* Pspe = (const float*)d_in[1];
  const float* q_w = (const float*)d_in[2];
  const float* q_b = (const float*)d_in[3];
  const float* k_w = (const float*)d_in[4];
  const float* k_b = (const float*)d_in[5];
  const float* v_w = (const float*)d_in[6];
  const float* v_b = (const float*)d_in[7];
  const float* f1_w = (const float*)d_in[8];
  const float* f1_b = (const float*)d_in[9];
  const float* f2_w = (const float*)d_in[10];
  const float* f2_b = (const float*)d_in[11];
  float* out = (float*)d_out;

  char* ws = (char*)d_ws;
  // padded buffer: 16*66*66*128*2 = 17,842,176 B; packed Q/K/V: 16,777,216 B
  const size_t XPO = 0;                      // Xp; SP aliases; Fp aliases
  const size_t QPO = 17842176;               // QP; Hp aliases (spills 1.06MB into KP head)
  const size_t KPO = QPO + 16777216;         // KP; ABP at head; Mpk at +1179648
  const size_t VO  = KPO + 16777216;
  const size_t WPO = VO + 16777216;          // ends at ~69.65 MB

  u16* Xp = (u16*)(ws + XPO);
  u16* QP = (u16*)(ws + QPO);
  u16* KP = (u16*)(ws + KPO);
  u16* V = (u16*)(ws + VO);
  u16* Wpk = (u16*)(ws + WPO);
  float* SP = (float*)(ws + XPO);   // 8.39 MB, Xp dead by then
  u16* ABP = KP;                    // 512 KB, KP dead by then
  u16* Mpk = (u16*)(ws + KPO + 1179648);
  u16* Fp = Xp;                     // padded F_ssm (f3 out; SP dead; borders re-zeroed by f3)
  u16* Hp = QP;                     // padded hidden (QP dead after attn_s)

  pack_xw<<<1644, 256, 0, stream>>>(F_in, Xp, q_w, k_w, v_w, f1_w, f2_w, Wpk);
  conv_qkv<<<1024, 256, 0, stream>>>(Xp, Wpk, q_b, k_b, v_b, QP, KP, V);
  attn_s<<<128, 256, 0, stream>>>(QP, KP, SP);
  attn_r<<<64, 256, 0, stream>>>(SP, ABP);
  attn_m<<<16, 256, 0, stream>>>(Pspe, ABP, Mpk);
  f3_gemm<<<512, 256, 0, stream>>>(V, Mpk, Fp, Hp);
  conv_ffn<1><<<512, 256, 0, stream>>>(Fp, Wpk + 3 * 147456, f1_b, Hp, nullptr, nullptr);
  conv_ffn<2><<<512, 256, 0, stream>>>(Hp, Wpk + 4 * 147456, f2_b, nullptr, out, Fp);
}

// Round 6
// 171.623 us; speedup vs baseline: 1.6219x; 1.6219x over previous
//
#include <hip/hip_runtime.h>
#include <cmath>

typedef unsigned short u16;
typedef __bf16 bf16x8 __attribute__((ext_vector_type(8)));
typedef float f32x4 __attribute__((ext_vector_type(4)));

__device__ __forceinline__ u16 f2bf(float f) {
  unsigned u = __float_as_uint(f);
  u += 0x7fffu + ((u >> 16) & 1u);
  return (u16)(u >> 16);
}
__device__ __forceinline__ float bf2f(u16 h) {
  return __uint_as_float(((unsigned)h) << 16);
}
__device__ __forceinline__ f32x4 mfma_bf16(bf16x8 a, bf16x8 b, f32x4 c) {
  return __builtin_amdgcn_mfma_f32_16x16x32_bf16(a, b, c, 0, 0, 0);
}
__device__ __forceinline__ float gelu_exact(float x) {
  return 0.5f * x * (1.0f + erff(x * 0.70710678118654752440f));
}

#define VMCNT2() asm volatile("s_waitcnt vmcnt(2)" ::: "memory")
#define VMCNT0() asm volatile("s_waitcnt vmcnt(0)" ::: "memory")
#define BARR()                                  \
  do {                                          \
    asm volatile("" ::: "memory");              \
    __builtin_amdgcn_s_barrier();               \
    asm volatile("" ::: "memory");              \
  } while (0)

__device__ __forceinline__ void gload16(const void* g, void* l) {
  __builtin_amdgcn_global_load_lds(
      (const __attribute__((address_space(1))) unsigned*)g,
      (__attribute__((address_space(3))) unsigned*)l, 16, 0, 0);
}

// B=16, C=128, H=64, W=64. Padded NHWC: [B][66][66][128], data at y+1,x+1.
__device__ __forceinline__ size_t pidx(int b, int y, int x) {
  return ((size_t)(b * 66 + y) * 66 + x) * 128;
}

__device__ __forceinline__ void border_yx(int k, int& y, int& x) {
  if (k < 66) { y = 0; x = k; }
  else if (k < 132) { y = 65; x = k - 66; }
  else if (k < 196) { y = k - 131; x = 0; }
  else { y = k - 195; x = 65; }
}

// ---------------- pack: X -> padded NHWC bf16, weights -> B-frag, X borders=0
__global__ __launch_bounds__(256) void pack_xw(
    const float* __restrict__ Fin, u16* __restrict__ Xp,
    const float* __restrict__ w0, const float* __restrict__ w1,
    const float* __restrict__ w2, const float* __restrict__ w3,
    const float* __restrict__ w4, u16* __restrict__ Wpk) {
  const int tid = threadIdx.x;
  const int bid = blockIdx.x;
  if (bid < 1024) {
    __shared__ float T[64 * 129];
    const int b = bid >> 6, y = bid & 63;
#pragma unroll
    for (int i = 0; i < 32; ++i) {
      int idx = tid + i * 256;
      int c = idx >> 6, x = idx & 63;
      T[x * 129 + c] = Fin[(size_t)(b * 128 + c) * 4096 + y * 64 + x];
    }
    __syncthreads();
#pragma unroll
    for (int i = 0; i < 4; ++i) {
      int chunk = tid + i * 256;
      int x = chunk >> 4;
      int c0 = (chunk & 15) * 8;
      u16 tmp[8];
#pragma unroll
      for (int e = 0; e < 8; ++e) tmp[e] = f2bf(T[x * 129 + c0 + e]);
      *reinterpret_cast<uint4*>(Xp + pidx(b, y + 1, x + 1) + c0) =
          *reinterpret_cast<const uint4*>(tmp);
    }
  } else if (bid < 1384) {
    int gid = (bid - 1024) * 256 + tid;  // 92160 total
    int lane = gid & 63;
    int nblk = (gid >> 6) & 7;
    int step = (gid >> 9) % 36;
    int conv = gid / (512 * 36);
    if (conv >= 5) return;
    const float* w = conv == 0 ? w0 : conv == 1 ? w1 : conv == 2 ? w2 : conv == 3 ? w3 : w4;
    int tap = step >> 2, cc = step & 3;
    int dy = tap / 3, dx = tap % 3;
    int co = nblk * 16 + (lane & 15);
    int ci0 = cc * 32 + (lane >> 4) * 8;
    u16 tmp[8];
#pragma unroll
    for (int e = 0; e < 8; ++e)
      tmp[e] = f2bf(w[((size_t)(co * 128 + ci0 + e) * 3 + dy) * 3 + dx]);
    size_t off = ((size_t)conv * 36 * 8 * 64 + (size_t)((step * 8 + nblk) * 64 + lane)) * 8;
    *reinterpret_cast<uint4*>(Wpk + off) = *reinterpret_cast<const uint4*>(tmp);
  } else {
    // zero Xp borders: 4160 positions of 256B
    int p = (bid - 1384) * 16 + (tid >> 4);
    int b = p / 260, k = p % 260;
    int y, x;
    border_yx(k, y, x);
    *reinterpret_cast<uint4*>(Xp + pidx(b, y, x) + (tid & 15) * 8) =
        make_uint4(0u, 0u, 0u, 0u);
  }
}

// ---------------- conv3x3 implicit GEMM, counted-vmcnt pipeline -------------
// M128 x N128 per block, 4 waves, acc 64 VGPR/wave.
// A: half-C tile (4 rows x 66 x 64ch) in LDS, XOR-swizzled via pre-swizzled src.
// B: per-step 8KB fragments in 3-slot LDS ring, staged 2 steps ahead.
// MODE 0: QKV (grid = 1536: conv = bid>>9; Q/K packed, V natural)
// MODE 1: f1 (gelu -> padded Hp)
// MODE 2: f2 (f32 NCHW + residual)
template <int MODE>
__global__ __launch_bounds__(256, 2) void conv5(
    const u16* __restrict__ Xin, const u16* __restrict__ Wp0,
    const float* __restrict__ bq, const float* __restrict__ bk,
    const float* __restrict__ bv,
    u16* __restrict__ O0, u16* __restrict__ O1, u16* __restrict__ O2,
    float* __restrict__ OutF, const u16* __restrict__ Resid) {
  __shared__ alignas(16) char smem[58368];  // A 33792 | B-ring 3*8192
  char* Abuf = smem;
  char* Bring = smem + 33792;
  const int tid = threadIdx.x;
  const int lane = tid & 63, wv = tid >> 6;
  const int wm = wv >> 1, wn = wv & 1;
  const int lm = lane & 15, lq = lane >> 4;
  const int bid = blockIdx.x;
  const int cv = (MODE == 0) ? (bid >> 9) : 0;
  const int mtr = bid & 511;
  const int mt = (mtr & 7) * 64 + (mtr >> 3);  // XCD swizzle, bijective
  const int b = mt >> 5, yp = mt & 31;
  const u16* WpC = Wp0 + (size_t)cv * 147456;

  f32x4 acc[4][4];
#pragma unroll
  for (int i = 0; i < 4; ++i)
#pragma unroll
    for (int j = 0; j < 4; ++j) acc[i][j] = f32x4{0.f, 0.f, 0.f, 0.f};

  // stage half-C A tile: 264 rows (4 padded y x 66 x) x 64 ch = 2112 x 16B
  auto stageA = [&](int h) {
#pragma unroll
    for (int r = 0; r < 9; ++r) {
      int c = wv * 528 + r * 64 + lane;
      int row = c >> 3, c16 = c & 7;
      int ys = row / 66, xs = row - ys * 66;
      const u16* src =
          Xin + pidx(b, yp * 2 + ys, xs) + h * 64 + ((c16 ^ (xs & 7)) << 3);
      char* dst = Abuf + (wv * 528 + r * 64) * 16;
      if (r < 8)
        gload16(src, dst);
      else if (lane < 16)
        gload16(src, dst);
    }
  };
  // stage one K-step's B fragments (8KB) into ring slot t%3
  auto stageB = [&](int t, int h) {
    int ws = (t >> 1) * 4 + h * 2 + (t & 1);  // Wpk step index
    const u16* s0 = WpC + (size_t)ws * 4096 + (size_t)(wv * 128 + lane) * 8;
    char* d0 = Bring + (t % 3) * 8192 + wv * 2048;
    gload16(s0, d0);
    gload16(s0 + 512, d0 + 1024);
  };

#pragma unroll 1
  for (int h = 0; h < 2; ++h) {
    BARR();  // all waves done with previous A tile / kernel start
    stageA(h);
    stageB(0, h);
    stageB(1, h);
    VMCNT2();  // A + B0 complete, B1 may be in flight
    BARR();
#pragma unroll
    for (int t = 0; t < 18; ++t) {
      if (t > 0) {
        if (t < 17) VMCNT2(); else VMCNT0();
        BARR();
      }
      if (t + 2 < 18) stageB(t + 2, h);  // overwrites slot (t-1)%3: safe post-barrier
      const int tap = t >> 1, ccL = t & 1;
      const int dy = tap / 3, dx = tap % 3;
      bf16x8 af[4], bfr[4];
#pragma unroll
      for (int i = 0; i < 4; ++i) {
        int p = wm * 64 + i * 16 + lm;
        int xs = (p & 63) + dx, ys = (p >> 6) + dy;
        unsigned off = (unsigned)(((ys * 66 + xs) * 64 + ccL * 32 + lq * 8) * 2) ^
                       (unsigned)((xs & 7) << 4);
        af[i] = *reinterpret_cast<const bf16x8*>(Abuf + off);
      }
      const char* bb = Bring + (t % 3) * 8192;
#pragma unroll
      for (int j = 0; j < 4; ++j)
        bfr[j] = *reinterpret_cast<const bf16x8*>(
            bb + ((wn * 4 + j) * 64 + lane) * 16);
#pragma unroll
      for (int i = 0; i < 4; ++i)
#pragma unroll
        for (int j = 0; j < 4; ++j) acc[i][j] = mfma_bf16(af[i], bfr[j], acc[i][j]);
    }
  }

  __syncthreads();  // LDS dead; reuse for epilogues

  if (MODE == 0 && cv < 2) {
    // Q/K fragment-packed epilogue
    const float* bias = cv == 0 ? bq : bk;
    u16* OutB = cv == 0 ? O0 : O1;
    u16* T = (u16*)smem;  // [128][136]
#pragma unroll
    for (int i = 0; i < 4; ++i)
#pragma unroll
      for (int j = 0; j < 4; ++j) {
        int n = wn * 64 + j * 16 + lm;
        float bs = bias[n];
#pragma unroll
        for (int r = 0; r < 4; ++r) {
          int m = wm * 64 + i * 16 + lq * 4 + r;
          T[n * 136 + m] = f2bf(acc[i][j][r] + bs);
        }
      }
    __syncthreads();
#pragma unroll
    for (int it = 0; it < 8; ++it) {
      int item = tid + it * 256;
      int l = item & 63, cb = (item >> 6) & 7, ksl = item >> 9;
      int c = cb * 16 + (l & 15);
      int mloc = ksl * 32 + (l >> 4) * 8;
      int ks = yp * 4 + ksl;
      *reinterpret_cast<uint4*>(
          OutB + (size_t)(((b * 128 + ks) * 8 + cb) * 64 + l) * 8) =
          *reinterpret_cast<const uint4*>(T + c * 136 + mloc);
    }
  } else if (MODE == 0) {
    // V natural [pos][ch]
    u16* T = (u16*)smem;  // [128][136]
#pragma unroll
    for (int i = 0; i < 4; ++i)
#pragma unroll
      for (int j = 0; j < 4; ++j) {
        int n = wn * 64 + j * 16 + lm;
        float bs = bv[n];
#pragma unroll
        for (int r = 0; r < 4; ++r) {
          int m = wm * 64 + i * 16 + lq * 4 + r;
          T[m * 136 + n] = f2bf(acc[i][j][r] + bs);
        }
      }
    __syncthreads();
    int rr = tid >> 1, hf = tid & 1;
    const uint4* src = reinterpret_cast<const uint4*>(T + rr * 136 + hf * 64);
    uint4* dst = reinterpret_cast<uint4*>(O2 + ((size_t)(mt * 128 + rr) * 128 + hf * 64));
#pragma unroll
    for (int k = 0; k < 8; ++k) dst[k] = src[k];
  } else if (MODE == 1) {
    // gelu -> padded Hp
    u16* T = (u16*)smem;  // [128][136]
#pragma unroll
    for (int i = 0; i < 4; ++i)
#pragma unroll
      for (int j = 0; j < 4; ++j) {
        int n = wn * 64 + j * 16 + lm;
        float bs = bq[n];
#pragma unroll
        for (int r = 0; r < 4; ++r) {
          int m = wm * 64 + i * 16 + lq * 4 + r;
          T[m * 136 + n] = f2bf(gelu_exact(acc[i][j][r] + bs));
        }
      }
    __syncthreads();
    int rr = tid >> 1, hf = tid & 1;
    int y = yp * 2 + (rr >> 6), x = rr & 63;
    const uint4* src = reinterpret_cast<const uint4*>(T + rr * 136 + hf * 64);
    uint4* dst = reinterpret_cast<uint4*>(O0 + pidx(b, y + 1, x + 1) + hf * 64);
#pragma unroll
    for (int k = 0; k < 8; ++k) dst[k] = src[k];
  } else {
    // f32 NCHW + residual, two N-halves through LDS transpose
    float* Tf = (float*)smem;  // [64][132] = 33792B
#pragma unroll
    for (int jh = 0; jh < 2; ++jh) {
      if (jh) __syncthreads();
#pragma unroll
      for (int i = 0; i < 4; ++i)
#pragma unroll
        for (int j2 = 0; j2 < 2; ++j2) {
          int j = jh * 2 + j2;
          int n = wn * 64 + j * 16 + lm;
          int nl = wn * 32 + j2 * 16 + lm;
          float bs = bq[n];
          int m0 = wm * 64 + i * 16 + lq * 4;
          int y = yp * 2 + (m0 >> 6), x = m0 & 63;
          const u16* rp = Resid + pidx(b, y + 1, x + 1) + n;
#pragma unroll
          for (int r = 0; r < 4; ++r)
            Tf[nl * 132 + m0 + r] = acc[i][j][r] + bs + bf2f(rp[r * 128]);
        }
      __syncthreads();
      int nl = tid >> 2, seg = tid & 3;
      int gn = (nl >> 5) * 64 + jh * 32 + (nl & 31);
      float* dst = OutF + ((size_t)(b * 128 + gn) * 4096 + yp * 128 + seg * 32);
      const float* src = Tf + nl * 132 + seg * 32;
#pragma unroll
      for (int k = 0; k < 8; ++k)
        reinterpret_cast<float4*>(dst)[k] = reinterpret_cast<const float4*>(src)[k];
    }
  }
}

// ---------------- S = K^T Q, split-K=8 -> f32 partials ----------------
__global__ __launch_bounds__(256, 2) void attn_s(const u16* __restrict__ QP,
                                                 const u16* __restrict__ KP,
                                                 float* __restrict__ SP) {
  const int tid = threadIdx.x;
  const int lane = tid & 63;
  const int wv = tid >> 6, wm = wv >> 1, wn = wv & 1;
  const int lm = lane & 15, lq = lane >> 4;
  int mt = blockIdx.x;
  mt = (mt & 7) * 16 + (mt >> 3);  // 128 blocks, bijective
  const int b = mt >> 3, sp = mt & 7;

  f32x4 acc[4][4];
#pragma unroll
  for (int i = 0; i < 4; ++i)
#pragma unroll
    for (int j = 0; j < 4; ++j) acc[i][j] = f32x4{0.f, 0.f, 0.f, 0.f};

#pragma unroll
  for (int ksl = 0; ksl < 16; ++ksl) {
    const int ks = sp * 16 + ksl;
    bf16x8 af[4], bfr[4];
#pragma unroll
    for (int i = 0; i < 4; ++i)
      af[i] = *reinterpret_cast<const bf16x8*>(
          KP + (size_t)(((b * 128 + ks) * 8 + wm * 4 + i) * 64 + lane) * 8);
#pragma unroll
    for (int j = 0; j < 4; ++j)
      bfr[j] = *reinterpret_cast<const bf16x8*>(
          QP + (size_t)(((b * 128 + ks) * 8 + wn * 4 + j) * 64 + lane) * 8);
#pragma unroll
    for (int i = 0; i < 4; ++i)
#pragma unroll
      for (int j = 0; j < 4; ++j) acc[i][j] = mfma_bf16(af[i], bfr[j], acc[i][j]);
  }

  float* out = SP + (size_t)(b * 8 + sp) * 16384;
#pragma unroll
  for (int i = 0; i < 4; ++i)
#pragma unroll
    for (int j = 0; j < 4; ++j)
#pragma unroll
      for (int r = 0; r < 4; ++r)
        out[(wm * 64 + i * 16 + lq * 4 + r) * 128 + wn * 64 + j * 16 + lm] =
            acc[i][j][r];
}

// ---------------- reduce partials + softmax + pack A ----------------
__global__ __launch_bounds__(256) void attn_r(const float* __restrict__ SP,
                                              u16* __restrict__ ABP) {
  __shared__ float Sf[32][129];
  __shared__ float Inv[32];
  const int tid = threadIdx.x;
  const int b = blockIdx.x >> 2, eb = blockIdx.x & 3;

#pragma unroll
  for (int it = 0; it < 16; ++it) {
    int id = it * 256 + tid;
    int rl = id >> 7, d = id & 127;
    const float* p = SP + (size_t)b * 8 * 16384 + (size_t)(eb * 32 + rl) * 128 + d;
    float s = 0.f;
#pragma unroll
    for (int sp = 0; sp < 8; ++sp) s += p[(size_t)sp * 16384];
    Sf[rl][d] = s * 0.015625f;
  }
  __syncthreads();

  {
    int rl = tid >> 3, sub = tid & 7;
    float mx = -3.4e38f;
#pragma unroll
    for (int k = 0; k < 16; ++k) mx = fmaxf(mx, Sf[rl][sub + 8 * k]);
    mx = fmaxf(mx, __shfl_xor(mx, 1));
    mx = fmaxf(mx, __shfl_xor(mx, 2));
    mx = fmaxf(mx, __shfl_xor(mx, 4));
    float s = 0.f;
#pragma unroll
    for (int k = 0; k < 16; ++k) {
      float e = __expf(Sf[rl][sub + 8 * k] - mx);
      Sf[rl][sub + 8 * k] = e;
      s += e;
    }
    s += __shfl_xor(s, 1);
    s += __shfl_xor(s, 2);
    s += __shfl_xor(s, 4);
    if (sub == 0) Inv[rl] = 1.0f / s;
  }
  __syncthreads();

#pragma unroll
  for (int it = 0; it < 2; ++it) {
    int item = tid + it * 256;
    int l = item & 63, nb = item >> 6;
    int d = nb * 16 + (l & 15);
    u16 tmp[8];
#pragma unroll
    for (int e = 0; e < 8; ++e) {
      int rloc = (l >> 4) * 8 + e;
      tmp[e] = f2bf(Sf[rloc][d] * Inv[rloc]);
    }
    *reinterpret_cast<uint4*>(ABP + (size_t)(((b * 4 + eb) * 8 + nb) * 64 + l) * 8) =
        *reinterpret_cast<const uint4*>(tmp);
  }
}

// ---------------- M = Pspe @ A, pack M ----------------
__global__ __launch_bounds__(256, 1) void attn_m(const float* __restrict__ Pspe,
                                                 const u16* __restrict__ ABP,
                                                 u16* __restrict__ Mpack) {
  __shared__ u16 Ml[128 * 136];
  const int b = blockIdx.x;
  const int tid = threadIdx.x;
  const int lane = tid & 63;
  const int wv = tid >> 6, wm = wv >> 1, wn = wv & 1;
  const int lm = lane & 15, lq = lane >> 4;

  f32x4 acc[4][4];
#pragma unroll
  for (int i = 0; i < 4; ++i)
#pragma unroll
    for (int j = 0; j < 4; ++j) acc[i][j] = f32x4{0.f, 0.f, 0.f, 0.f};

  const float* P = Pspe + (size_t)b * 128 * 128;
#pragma unroll
  for (int cc = 0; cc < 4; ++cc) {
    int e0 = cc * 32 + lq * 8;
    bf16x8 af[4], bfr[4];
#pragma unroll
    for (int i = 0; i < 4; ++i) {
      const float* p = P + (size_t)(wm * 64 + i * 16 + lm) * 128 + e0;
      union { u16 u[8]; bf16x8 v; } cvu;
#pragma unroll
      for (int e = 0; e < 8; ++e) cvu.u[e] = f2bf(p[e]);
      af[i] = cvu.v;
    }
#pragma unroll
    for (int j = 0; j < 4; ++j)
      bfr[j] = *reinterpret_cast<const bf16x8*>(
          ABP + (size_t)(((b * 4 + cc) * 8 + wn * 4 + j) * 64 + lane) * 8);
#pragma unroll
    for (int i = 0; i < 4; ++i)
#pragma unroll
      for (int j = 0; j < 4; ++j) acc[i][j] = mfma_bf16(af[i], bfr[j], acc[i][j]);
  }

#pragma unroll
  for (int i = 0; i < 4; ++i)
#pragma unroll
    for (int j = 0; j < 4; ++j)
#pragma unroll
      for (int r = 0; r < 4; ++r)
        Ml[(wn * 64 + j * 16 + lm) * 136 + (wm * 64 + i * 16 + lq * 4 + r)] =
            f2bf(acc[i][j][r]);
  __syncthreads();

#pragma unroll
  for (int it = 0; it < 8; ++it) {
    int item = tid + it * 256;
    int l2 = item & 63, nb = (item >> 6) & 7, cc2 = item >> 9;
    int d = nb * 16 + (l2 & 15), c0 = cc2 * 32 + (l2 >> 4) * 8;
    *reinterpret_cast<uint4*>(Mpack + (size_t)b * 16384 + (size_t)item * 8) =
        *reinterpret_cast<const uint4*>(Ml + d * 136 + c0);
  }
}

// ---------------- F3 = V @ M -> Fp (padded) + zero Fp/Hp borders ----------
__global__ __launch_bounds__(256) void f3_gemm(const u16* __restrict__ V,
                                               const u16* __restrict__ Mpack,
                                               u16* __restrict__ Fp,
                                               u16* __restrict__ Hp) {
  const int tid = threadIdx.x;
  const int lane = tid & 63;
  const int wv = tid >> 6, wm = wv >> 1, wn = wv & 1;
  const int lm = lane & 15, lq = lane >> 4;
  const int bid = blockIdx.x;
  int mt = bid;
  mt = (mt & 7) * 64 + (mt >> 3);
  const int b = mt >> 5;
  const int yp = mt & 31;

  f32x4 acc[4][4];
#pragma unroll
  for (int i = 0; i < 4; ++i)
#pragma unroll
    for (int j = 0; j < 4; ++j) acc[i][j] = f32x4{0.f, 0.f, 0.f, 0.f};

#pragma unroll
  for (int cc = 0; cc < 4; ++cc) {
    int k0 = cc * 32 + lq * 8;
    bf16x8 af[4], bfr[4];
#pragma unroll
    for (int i = 0; i < 4; ++i)
      af[i] = *reinterpret_cast<const bf16x8*>(
          V + (size_t)(mt * 128 + wm * 64 + i * 16 + lm) * 128 + k0);
#pragma unroll
    for (int j = 0; j < 4; ++j)
      bfr[j] = *reinterpret_cast<const bf16x8*>(
          Mpack + (size_t)b * 16384 + (size_t)((cc * 8 + wn * 4 + j) * 64 + lane) * 8);
#pragma unroll
    for (int i = 0; i < 4; ++i)
#pragma unroll
      for (int j = 0; j < 4; ++j) acc[i][j] = mfma_bf16(af[i], bfr[j], acc[i][j]);
  }

  // zero borders of Fp and Hp
#pragma unroll
  for (int rep = 0; rep < 2; ++rep) {
    int p = bid * 32 + rep * 16 + (tid >> 4);
    if (p < 8320) {
      u16* buf = p < 4160 ? Fp : Hp;
      int q = p < 4160 ? p : p - 4160;
      int bb = q / 260, k = q % 260;
      int y, x;
      border_yx(k, y, x);
      *reinterpret_cast<uint4*>(buf + pidx(bb, y, x) + (tid & 15) * 8) =
          make_uint4(0u, 0u, 0u, 0u);
    }
  }

  __shared__ u16 T[128 * 136];
#pragma unroll
  for (int i = 0; i < 4; ++i)
#pragma unroll
    for (int j = 0; j < 4; ++j)
#pragma unroll
      for (int r = 0; r < 4; ++r)
        T[(wm * 64 + i * 16 + lq * 4 + r) * 136 + wn * 64 + j * 16 + lm] =
            f2bf(acc[i][j][r]);
  __syncthreads();
  int rr = tid >> 1, hf = tid & 1;
  int y = yp * 2 + (rr >> 6), x = rr & 63;
  const uint4* src = reinterpret_cast<const uint4*>(T + rr * 136 + hf * 64);
  uint4* dst = reinterpret_cast<uint4*>(Fp + pidx(b, y + 1, x + 1) + hf * 64);
#pragma unroll
  for (int k = 0; k < 8; ++k) dst[k] = src[k];
}

extern "C" void kernel_launch(void* const* d_in, const int* in_sizes, int n_in,
                              void* d_out, int out_size, void* d_ws, size_t ws_size,
                              hipStream_t stream) {
  const float* F_in = (const float*)d_in[0];
  const float* Pspe = (const float*)d_in[1];
  const float* q_w = (const float*)d_in[2];
  const float* q_b = (const float*)d_in[3];
  const float* k_w = (const float*)d_in[4];
  const float* k_b = (const float*)d_in[5];
  const float* v_w = (const float*)d_in[6];
  const float* v_b = (const float*)d_in[7];
  const float* f1_w = (const float*)d_in[8];
  const float* f1_b = (const float*)d_in[9];
  const float* f2_w = (const float*)d_in[10];
  const float* f2_b = (const float*)d_in[11];
  float* out = (float*)d_out;

  char* ws = (char*)d_ws;
  // padded buffer: 16*66*66*128*2 = 17,842,176 B; packed Q/K/V: 16,777,216 B each
  const size_t XPO = 0;
  const size_t QPO = 17842176;
  const size_t KPO = QPO + 16777216;
  const size_t VO  = KPO + 16777216;
  const size_t WPO = VO + 16777216;

  u16* Xp = (u16*)(ws + XPO);
  u16* QP = (u16*)(ws + QPO);
  u16* KP = (u16*)(ws + KPO);
  u16* V = (u16*)(ws + VO);
  u16* Wpk = (u16*)(ws + WPO);
  float* SP = (float*)(ws + XPO);   // 8.39 MB partials — aliases Xp (dead)
  u16* ABP = KP;                    // aliases KP (dead after attn_s)
  u16* Mpk = (u16*)(ws + KPO + 1179648);
  u16* Fp = Xp;                     // padded F_ssm
  u16* Hp = QP;                     // padded hidden

  pack_xw<<<1644, 256, 0, stream>>>(F_in, Xp, q_w, k_w, v_w, f1_w, f2_w, Wpk);
  conv5<0><<<1536, 256, 0, stream>>>(Xp, Wpk, q_b, k_b, v_b, QP, KP, V, nullptr, nullptr);
  attn_s<<<128, 256, 0, stream>>>(QP, KP, SP);
  attn_r<<<64, 256, 0, stream>>>(SP, ABP);
  attn_m<<<16, 256, 0, stream>>>(Pspe, ABP, Mpk);
  f3_gemm<<<512, 256, 0, stream>>>(V, Mpk, Fp, Hp);
  conv5<1><<<512, 256, 0, stream>>>(Fp, Wpk + 3 * 147456, f1_b, nullptr, nullptr,
                                    Hp, nullptr, nullptr, nullptr, nullptr);
  conv5<2><<<512, 256, 0, stream>>>(Hp, Wpk + 4 * 147456, f2_b, nullptr, nullptr,
                                    nullptr, nullptr, nullptr, out, Fp);
}